// Round 4
// baseline (2903.452 us; speedup 1.0000x reference)
//
#include <hip/hip_runtime.h>
#include <stdint.h>

typedef unsigned short ushort_t;
typedef unsigned long long ull_t;
typedef __attribute__((ext_vector_type(8))) short short8;      // 8 bf16 (4 VGPRs)
typedef __attribute__((ext_vector_type(2))) unsigned long long ull2;
typedef __attribute__((ext_vector_type(4))) float f32x4;       // MFMA 16x16 acc
typedef __attribute__((ext_vector_type(4))) float float4v;
typedef __attribute__((ext_vector_type(4))) unsigned short ushort4v;
typedef __attribute__((ext_vector_type(4))) unsigned int uint4v;

#define NB 64
#define NT 512
#define ND 1024
#define NHH 1024
#define NG 4096

__device__ __forceinline__ ushort_t f2bf(float x) {
    uint32_t u = __builtin_bit_cast(uint32_t, x);
    u += 0x7fffu + ((u >> 16) & 1u);   // RTNE
    return (ushort_t)(u >> 16);
}
__device__ __forceinline__ float bf2f(ushort_t b) {
    uint32_t u = ((uint32_t)b) << 16;
    return __builtin_bit_cast(float, u);
}
__device__ __forceinline__ float fsigmoid(float x) { return 1.f / (1.f + __expf(-x)); }
__device__ __forceinline__ float ftanh(float x) {
    float ax = __builtin_fabsf(x);
    float e = __expf(-2.f * ax);
    float r = (1.f - e) / (1.f + e);
    return x < 0.f ? -r : r;
}
__device__ __forceinline__ void xg_store(float* p, float v) { *p = v; }
__device__ __forceinline__ void xg_store(ushort_t* p, float v) { *p = f2bf(v); }
__device__ __forceinline__ float4v xg_load4(const float4v* p) { return *p; }
__device__ __forceinline__ float4v xg_load4(const ushort4v* p) {
    ushort4v u = *p;
    float4v r = { bf2f(u[0]), bf2f(u[1]), bf2f(u[2]), bf2f(u[3]) };
    return r;
}
// async global->LDS 16B copy: LDS dest is wave-uniform base + lane*16
__device__ __forceinline__ void async_cp16(const ushort_t* g, ushort_t* s) {
    __builtin_amdgcn_global_load_lds(
        (const __attribute__((address_space(1))) uint32_t*)g,
        (__attribute__((address_space(3))) uint32_t*)s, 16, 0, 0);
}

// ---------------- prep: IDENTICAL to the proven R1 version (footprint frozen).
__global__ __launch_bounds__(256) void k_prep(
    const float* __restrict__ feat, const float* __restrict__ wih,
    const float* __restrict__ whh,
    ushort_t* __restrict__ featb, ushort_t* __restrict__ wihb,
    ushort_t* __restrict__ whhb, ushort_t* __restrict__ hbuf,
    int* __restrict__ cnt)
{
    const size_t NF = (size_t)NB * NT * ND / 4;   // 8388608 float4 chunks
    const size_t NW = (size_t)NG * ND / 4;        // 1048576
    const size_t NHB = (size_t)2 * 65536 * 2 / 16; // 16384 16B chunks
    size_t total = NF + 2 * NW + NHB;
    size_t stride = (size_t)gridDim.x * blockDim.x;
    for (size_t i = (size_t)blockIdx.x * blockDim.x + threadIdx.x; i < total; i += stride) {
        if (i < NF) {
            float4v v = ((const float4v*)feat)[i];
            ushort4v o = { f2bf(v[0]), f2bf(v[1]), f2bf(v[2]), f2bf(v[3]) };
            ((ushort4v*)featb)[i] = o;
        } else if (i < NF + NW) {
            size_t j = i - NF;                      // chunk over [4096 rows][256 f4]
            size_t row = j >> 8, kc = j & 255;
            size_t rowp = ((row & 1023) << 2) | (row >> 10);   // j*4 + gate
            float4v v = ((const float4v*)wih)[j];
            ushort4v o = { f2bf(v[0]), f2bf(v[1]), f2bf(v[2]), f2bf(v[3]) };
            ((ushort4v*)wihb)[rowp * 256 + kc] = o;
        } else if (i < NF + 2 * NW) {
            size_t j = i - NF - NW;
            float4v v = ((const float4v*)whh)[j];
            ushort4v o = { f2bf(v[0]), f2bf(v[1]), f2bf(v[2]), f2bf(v[3]) };
            ((ushort4v*)whhb)[j] = o;
        } else {
            size_t j = i - NF - 2 * NW;
            uint4v z = { 0u, 0u, 0u, 0u };
            ((uint4v*)hbuf)[j] = z;
        }
    }
    // Zero the FULL 4096-int flag region (16 blocks x 256 threads).
    if (blockIdx.x < 16) cnt[blockIdx.x * 256 + threadIdx.x] = 0;
}

// ---------------- x_gates GEMM: IDENTICAL to the proven R1 version.
template <typename XGT>
__global__ __launch_bounds__(256) void k_gemm(
    const ushort_t* __restrict__ Ab,   // feature bf16 [32768][1024]
    const ushort_t* __restrict__ Bb,   // W_ih' bf16 [4096][1024] (row-permuted)
    const float* __restrict__ bih, const float* __restrict__ bhh,
    const int* __restrict__ slenp, XGT* __restrict__ xg)
{
    int bid = blockIdx.x;                  // 8192 tiles
    int panel = bid >> 8;                  // 32 panels of (8 mt x 32 nt) for L2 reuse
    int qq = bid & 255;
    int mt = (panel << 3) | (qq & 7);
    int nt = qq >> 3;
    int m0 = mt << 7, n0 = nt << 7;
    int b = m0 >> 9;                       // 128-row tile lies within one batch
    int t0 = m0 & 511;
    int sl = slenp[b];
    if (t0 >= sl) return;                  // whole tile masked: xg never read there

    __shared__ short8 ldsA8[1024];         // 128 rows x 8 chunks (16 KB), swizzled
    __shared__ short8 ldsB8[1024];
    ushort_t* ldsA = (ushort_t*)ldsA8;
    ushort_t* ldsB = (ushort_t*)ldsB8;
    const ushort_t* gA = Ab + (size_t)m0 * 1024;
    const ushort_t* gB = Bb + (size_t)n0 * 1024;

    int tid = threadIdx.x;
    int wave = tid >> 6, lane = tid & 63;
    int wm = (wave >> 1) << 6;
    int wn = (wave & 1) << 6;
    int fl = lane & 15, fq = lane >> 4;

    f32x4 acc[4][4];
#pragma unroll
    for (int i = 0; i < 4; i++)
#pragma unroll
        for (int j = 0; j < 4; j++) { f32x4 z = {0.f, 0.f, 0.f, 0.f}; acc[i][j] = z; }

    // per-thread staging coords: slot s = u*256 + tid; row = s>>3, kb = (s&7)^(row&7)
    int srow_[4], skb_[4];
#pragma unroll
    for (int u = 0; u < 4; u++) {
        int s = u * 256 + tid;
        srow_[u] = s >> 3;
        skb_[u] = (s & 7) ^ (srow_[u] & 7);
    }

    for (int k0 = 0; k0 < 1024; k0 += 64) {
        if (k0) __syncthreads();           // protect LDS from previous iter's reads
#pragma unroll
        for (int u = 0; u < 4; u++) {
            ushort_t* sa = ldsA + (size_t)(u * 256 + wave * 64) * 8;
            ushort_t* sb = ldsB + (size_t)(u * 256 + wave * 64) * 8;
            async_cp16(gA + (size_t)srow_[u] * 1024 + k0 + skb_[u] * 8, sa);
            async_cp16(gB + (size_t)srow_[u] * 1024 + k0 + skb_[u] * 8, sb);
        }
        __syncthreads();                   // drains vmcnt: LDS tiles ready
#pragma unroll
        for (int ks = 0; ks < 2; ks++) {
            int kc = ks * 4 + fq;          // 16B chunk within BK=64
            short8 af[4], bf[4];
#pragma unroll
            for (int i = 0; i < 4; i++) {
                int ra = wm + i * 16 + fl;
                int rb = wn + i * 16 + fl;
                af[i] = ldsA8[ra * 8 + (kc ^ (ra & 7))];
                bf[i] = ldsB8[rb * 8 + (kc ^ (rb & 7))];
            }
#pragma unroll
            for (int i = 0; i < 4; i++)
#pragma unroll
                for (int j = 0; j < 4; j++)
                    acc[i][j] = __builtin_amdgcn_mfma_f32_16x16x32_bf16(af[i], bf[j], acc[i][j], 0, 0, 0);
        }
    }
    // epilogue: C layout col=lane&15, row=quad*4+reg. Columns are permuted rows rp.
#pragma unroll
    for (int j = 0; j < 4; j++) {
        int rp = n0 + wn + j * 16 + fl;              // permuted row index
        int bi = ((rp & 3) << 10) | (rp >> 2);       // gate*1024 + j
        float bv = bih[bi] + bhh[bi];
#pragma unroll
        for (int i = 0; i < 4; i++) {
#pragma unroll
            for (int r = 0; r < 4; r++) {
                int m = wm + i * 16 + fq * 4 + r;
                int t = t0 + m;
                if (t < sl)
                    xg_store(&xg[((size_t)t * 64 + b) * 4096 + rp], acc[i][j][r] + bv);
            }
        }
    }
}

// ---------------- persistent recurrence: FAT WGs, proven R1 flag protocol.
// 128 WGs x 512 thr. Group mb = wg>>5 owns 16 batches; member mem = wg&31 owns
// 32 j. Per step each WG loads the group's FULL 32KB h-tile once (64B/thread,
// contiguous, agent-scope atomic ulls — R1's proven primitive/layout), stages
// to LDS, and all 8 waves = (jb 0..1)x(ks 0..3) consume it (R1's proven wfrag
// shape: 16 j x 4 gates x K-quarter, 128 VGPR).
// Sync: per-WAVE flags, published after a per-wave vmcnt(0) drain of its 64
// 2B h-stores (R1's exact publish). Consumer thread's 64B (4 chunks: jc=tid>>2,
// b-quad q4=tid&3) is covered by exactly 2 producer wave-flags, ADJACENT in
// memory -> the whole spin is ONE 8-byte atomic load per poll.
// Skew<=1: bar C joins 512 threads whose spins collectively cover ALL 256
// producer wave-flags >= t; flag(m,w) >= t => that wave passed bar F(t-1) <=
// bar C(t-1) => its WG finished ALL h(t-1) loads => overwriting parity (t+1)&1
// (== (t-1)&1) is safe. Identical proof shape to the passing R1 kernel.
// Drain hygiene: xg prefetch issued at TOP (absorbed into spin); out store
// AFTER flag publish (off the publish drain).
template <typename XG4>
__global__ __launch_bounds__(512, 2) void k_rec(
    const ushort_t* __restrict__ whhb, const XG4* __restrict__ xg4,
    const int* __restrict__ slenp, ushort_t* __restrict__ hbuf,
    float* __restrict__ out, int* __restrict__ cnt)
{
    const int tid = threadIdx.x;
    const int wg = blockIdx.x;         // 128
    const int mb = wg >> 5;            // 0..3 batch group
    const int mem = wg & 31;           // member within group
    const int j0 = mem << 5;           // 32 j per WG
    const int w = tid >> 6, lane = tid & 63;
    const int jb = w >> 2, ks = w & 3; // 2 j-blocks x 4 K-quarters
    const int nn = lane & 15, q = lane >> 4;

    // B-fragments: rows g*1024 + (j0 + jb*16 + nn), K-quarter ks (128 VGPR)
    short8 wfrag[4][8];
    {
        const short8* w8 = (const short8*)whhb;
        const int jw = j0 + (jb << 4);
#pragma unroll
        for (int g = 0; g < 4; g++) {
            const short8* wp = w8 + (size_t)(g * NHH + jw + nn) * 128 + ks * 32;
#pragma unroll
            for (int u = 0; u < 8; u++) wfrag[g][u] = wp[u * 4 + q];
        }
    }

    const int j_t = tid & 31, b_t = tid >> 5;   // epilogue thread -> (j, b)
    const int b_g = (mb << 4) + b_t;
    const int j_gl = j0 + j_t;
    const int slen = slenp[b_g];
    const int blk_len = slenp[mb << 4];          // seq_len sorted desc -> group max

    // consumer staging coords: 4 chunks (jc, b = mb*16 + q4*4 + i), 64B contiguous
    const int jc = tid >> 2, q4 = tid & 3;
    const size_t src_base = ((size_t)(jc * 64 + (mb << 4) + (q4 << 2))) << 1; // ull idx

    // flags: group region = 256 ints; flag (mem, wave) at mem*8 + wave.
    // This thread's 2 guarding flags = {(jc>>2)*8 + 2*q4, +1} -> one ull poll.
    int* flags = cnt + mb * 256;
    const ull_t* flagsU = (const ull_t*)flags;
    const int pollU = (jc >> 2) * 4 + q4;
    const int myflag = mem * 8 + w;

    __shared__ short8 A_lds8[2048];    // 32KB packed h tile: slot = c*16 + b_local
    __shared__ float red[4 * 2176];    // 34.8KB: [g][j32 stride68][b16*4][ks4]

    float c_st = 0.f, h_st = 0.f;
    float4v xv = { 0.f, 0.f, 0.f, 0.f };
    if (0 < slen) xv = xg_load4(&xg4[(size_t)b_g * 1024 + j_gl]);   // xg(0)

#pragma unroll 1
    for (int t = 0; t < blk_len; ++t) {
        // xg prefetch for t+1 at TOP: HBM latency absorbed by the spin window
        float4v nxv = { 0.f, 0.f, 0.f, 0.f };
        if (t + 1 < slen) nxv = xg_load4(&xg4[((size_t)(t + 1) * 64 + b_g) * 1024 + j_gl]);

        if (t > 0) {
            int guard = 0;
            while (true) {
                ull_t f = __hip_atomic_load(&flagsU[pollU], __ATOMIC_RELAXED, __HIP_MEMORY_SCOPE_AGENT);
                if ((int)(uint32_t)f >= t && (int)(uint32_t)(f >> 32) >= t) break;
                if (++guard > (1 << 20)) break;   // bounded: bug -> visible fail
            }
            asm volatile("" ::: "memory");   // keep h loads below the spin
        }
        // load this thread's 64B of h(t) (R1 layout, proven atomic ull loads)
        const ull_t* src = (const ull_t*)(hbuf + (size_t)(t & 1) * 65536) + src_base;
        ull_t v[8];
#pragma unroll
        for (int u2 = 0; u2 < 8; u2++)
            v[u2] = __hip_atomic_load(&src[u2], __ATOMIC_RELAXED, __HIP_MEMORY_SCOPE_AGENT);
#pragma unroll
        for (int i = 0; i < 4; i++) {
            ull2 p; p[0] = v[2 * i]; p[1] = v[2 * i + 1];
            A_lds8[tid * 4 + i] = __builtin_bit_cast(short8, p);   // slot jc*16+b_local
        }
        __syncthreads();   // bar C: tile staged; whole WG past its spins

        // MFMA: wave (jb,ks): af lane nn = h[b=mb*16+nn][8c..8c+7], c=ks*32+u*4+q
        f32x4 acc0 = { 0.f, 0.f, 0.f, 0.f };
        f32x4 acc1 = acc0, acc2 = acc0, acc3 = acc0;
#pragma unroll
        for (int u = 0; u < 8; u++) {
            short8 af = A_lds8[(ks * 32 + u * 4 + q) * 16 + nn];
            acc0 = __builtin_amdgcn_mfma_f32_16x16x32_bf16(af, wfrag[0][u], acc0, 0, 0, 0);
            acc1 = __builtin_amdgcn_mfma_f32_16x16x32_bf16(af, wfrag[1][u], acc1, 0, 0, 0);
            acc2 = __builtin_amdgcn_mfma_f32_16x16x32_bf16(af, wfrag[2][u], acc2, 0, 0, 0);
            acc3 = __builtin_amdgcn_mfma_f32_16x16x32_bf16(af, wfrag[3][u], acc3, 0, 0, 0);
        }
        // red: [g][jj stride68][b*4 + ks]; C layout col(nn)=j, row(q*4+r)=b
        {
            const int jj = (jb << 4) + nn;
#pragma unroll
            for (int r = 0; r < 4; r++) {
                int bo = jj * 68 + (q * 4 + r) * 4 + ks;
                red[0 * 2176 + bo] = acc0[r];
                red[1 * 2176 + bo] = acc1[r];
                red[2 * 2176 + bo] = acc2[r];
                red[3 * 2176 + bo] = acc3[r];
            }
        }
        __syncthreads();   // bar F: red ready; all A_lds reads of step t done

        float hv = 0.f;
        if (t < slen) {
            float s[4];
#pragma unroll
            for (int g = 0; g < 4; g++) {
                f32x4 pv = *(const f32x4*)&red[g * 2176 + j_t * 68 + b_t * 4];
                s[g] = (pv[0] + pv[1]) + (pv[2] + pv[3]);
            }
            float ip = s[0] + xv[0];
            float fp = s[1] + xv[1];
            float gp = s[2] + xv[2];
            float op = s[3] + xv[3];
            float i_s = fsigmoid(ip), f_s = fsigmoid(fp);
            float g_t = ftanh(gp), o_s = fsigmoid(op);
            float cn = __builtin_fmaf(f_s, c_st, i_s * g_t);
            c_st = cn;
            h_st = o_s * ftanh(cn);
            hv = h_st;
        }
        // h store (R1's exact 2B agent-scope atomic, R1 layout)
        __hip_atomic_store(&hbuf[(size_t)((t + 1) & 1) * 65536 +
                                 (size_t)((j_gl >> 3) * 64 + b_g) * 8 + (j_gl & 7)],
                           f2bf(h_st), __ATOMIC_RELAXED, __HIP_MEMORY_SCOPE_AGENT);
        // per-wave drain (h stores in L3), then publish this wave's flag
        asm volatile("s_waitcnt vmcnt(0)" ::: "memory");
        if (lane == 0)
            __hip_atomic_store(&flags[myflag], t + 1, __ATOMIC_RELAXED, __HIP_MEMORY_SCOPE_AGENT);
        // out store AFTER publish: off the critical drain; acks during next spin
        out[((size_t)b_g * NT + t) * 1024 + j_gl] = hv;
        xv = nxv;
    }
    // zero tail past blk_len
    for (int t2 = blk_len; t2 < NT; ++t2)
        out[((size_t)b_g * NT + t2) * 1024 + j_gl] = 0.f;
}

extern "C" void kernel_launch(void* const* d_in, const int* in_sizes, int n_in,
                              void* d_out, int out_size, void* d_ws, size_t ws_size,
                              hipStream_t stream)
{
    const float* feat = (const float*)d_in[0];
    const float* wih  = (const float*)d_in[1];
    const float* whh  = (const float*)d_in[2];
    const float* bih  = (const float*)d_in[3];
    const float* bhh  = (const float*)d_in[4];
    const int*   sl   = (const int*)d_in[5];
    float* out = (float*)d_out;
    char* ws = (char*)d_ws;

    size_t off = 0;
    auto take = [&](size_t bytes) -> size_t {
        size_t o = off; off += (bytes + 255) & ~(size_t)255; return o;
    };
    // FOOTPRINT FROZEN to the proven R1 layout (fp32-xg branch must not flip).
    size_t o_featb = take((size_t)NB * NT * ND * 2);  // 64 MiB
    size_t o_wihb  = take((size_t)NG * ND * 2);       // 8 MiB
    size_t o_whhb  = take((size_t)NG * ND * 2);       // 8 MiB
    size_t o_hbuf  = take((size_t)2 * 65536 * 2);     // 256 KiB (2 bf16 h buffers)
    size_t o_cnt   = take(16384);                     // flag region (1KB used/group)
    size_t o_xg    = off;

    ushort_t* featb = (ushort_t*)(ws + o_featb);
    ushort_t* wihb  = (ushort_t*)(ws + o_wihb);
    ushort_t* whhb  = (ushort_t*)(ws + o_whhb);
    ushort_t* hbuf  = (ushort_t*)(ws + o_hbuf);
    int* cnt        = (int*)(ws + o_cnt);

    k_prep<<<2048, 256, 0, stream>>>(feat, wih, whh, featb, wihb, whhb, hbuf, cnt);

    size_t xg_elems = (size_t)NT * NB * NG;
    bool f32xg = (o_xg + xg_elems * 4) <= ws_size;    // prefer fp32 xg for accuracy
    if (f32xg) {
        float* xg = (float*)(ws + o_xg);
        k_gemm<float><<<8192, 256, 0, stream>>>(featb, wihb, bih, bhh, sl, xg);
        k_rec<float4v><<<128, 512, 0, stream>>>(whhb, (const float4v*)xg, sl, hbuf, out, cnt);
    } else {
        ushort_t* xg = (ushort_t*)(ws + o_xg);
        k_gemm<ushort_t><<<8192, 256, 0, stream>>>(featb, wihb, bih, bhh, sl, xg);
        k_rec<ushort4v><<<128, 512, 0, stream>>>(whhb, (const ushort4v*)xg, sl, hbuf, out, cnt);
    }
}

// Round 5
// 2667.810 us; speedup vs baseline: 1.0883x; 1.0883x over previous
//
#include <hip/hip_runtime.h>
#include <stdint.h>

typedef unsigned short ushort_t;
typedef unsigned long long ull_t;
typedef __attribute__((ext_vector_type(8))) short short8;      // 8 bf16 (4 VGPRs)
typedef __attribute__((ext_vector_type(2))) unsigned long long ull2;
typedef __attribute__((ext_vector_type(4))) float f32x4;       // MFMA 16x16 acc
typedef __attribute__((ext_vector_type(4))) float float4v;
typedef __attribute__((ext_vector_type(4))) unsigned short ushort4v;
typedef __attribute__((ext_vector_type(4))) unsigned int uint4v;

#define NB 64
#define NT 512
#define ND 1024
#define NHH 1024
#define NG 4096

__device__ __forceinline__ ushort_t f2bf(float x) {
    uint32_t u = __builtin_bit_cast(uint32_t, x);
    u += 0x7fffu + ((u >> 16) & 1u);   // RTNE
    return (ushort_t)(u >> 16);
}
__device__ __forceinline__ float bf2f(ushort_t b) {
    uint32_t u = ((uint32_t)b) << 16;
    return __builtin_bit_cast(float, u);
}
__device__ __forceinline__ float fsigmoid(float x) { return 1.f / (1.f + __expf(-x)); }
__device__ __forceinline__ float ftanh(float x) {
    float ax = __builtin_fabsf(x);
    float e = __expf(-2.f * ax);
    float r = (1.f - e) / (1.f + e);
    return x < 0.f ? -r : r;
}
// agent-scope xg stores: cross-XCD producer->consumer within ONE dispatch
__device__ __forceinline__ void xg_astore(float* p, float v) {
    __hip_atomic_store(p, v, __ATOMIC_RELAXED, __HIP_MEMORY_SCOPE_AGENT);
}
__device__ __forceinline__ void xg_astore(ushort_t* p, float v) {
    __hip_atomic_store(p, f2bf(v), __ATOMIC_RELAXED, __HIP_MEMORY_SCOPE_AGENT);
}
__device__ __forceinline__ float4v xg_load4(const float4v* p) { return *p; }
__device__ __forceinline__ float4v xg_load4(const ushort4v* p) {
    ushort4v u = *p;
    float4v r = { bf2f(u[0]), bf2f(u[1]), bf2f(u[2]), bf2f(u[3]) };
    return r;
}
// async global->LDS 16B copy: LDS dest is wave-uniform base + lane*16
__device__ __forceinline__ void async_cp16(const ushort_t* g, ushort_t* s) {
    __builtin_amdgcn_global_load_lds(
        (const __attribute__((address_space(1))) uint32_t*)g,
        (__attribute__((address_space(3))) uint32_t*)s, 16, 0, 0);
}

// ---------------- prep: IDENTICAL to the proven R1 version (footprint frozen).
__global__ __launch_bounds__(256) void k_prep(
    const float* __restrict__ feat, const float* __restrict__ wih,
    const float* __restrict__ whh,
    ushort_t* __restrict__ featb, ushort_t* __restrict__ wihb,
    ushort_t* __restrict__ whhb, ushort_t* __restrict__ hbuf,
    int* __restrict__ cnt)
{
    const size_t NF = (size_t)NB * NT * ND / 4;   // 8388608 float4 chunks
    const size_t NW = (size_t)NG * ND / 4;        // 1048576
    const size_t NHB = (size_t)2 * 65536 * 2 / 16; // 16384 16B chunks
    size_t total = NF + 2 * NW + NHB;
    size_t stride = (size_t)gridDim.x * blockDim.x;
    for (size_t i = (size_t)blockIdx.x * blockDim.x + threadIdx.x; i < total; i += stride) {
        if (i < NF) {
            float4v v = ((const float4v*)feat)[i];
            ushort4v o = { f2bf(v[0]), f2bf(v[1]), f2bf(v[2]), f2bf(v[3]) };
            ((ushort4v*)featb)[i] = o;
        } else if (i < NF + NW) {
            size_t j = i - NF;                      // chunk over [4096 rows][256 f4]
            size_t row = j >> 8, kc = j & 255;
            size_t rowp = ((row & 1023) << 2) | (row >> 10);   // j*4 + gate
            float4v v = ((const float4v*)wih)[j];
            ushort4v o = { f2bf(v[0]), f2bf(v[1]), f2bf(v[2]), f2bf(v[3]) };
            ((ushort4v*)wihb)[rowp * 256 + kc] = o;
        } else if (i < NF + 2 * NW) {
            size_t j = i - NF - NW;
            float4v v = ((const float4v*)whh)[j];
            ushort4v o = { f2bf(v[0]), f2bf(v[1]), f2bf(v[2]), f2bf(v[3]) };
            ((ushort4v*)whhb)[j] = o;
        } else {
            size_t j = i - NF - 2 * NW;
            uint4v z = { 0u, 0u, 0u, 0u };
            ((uint4v*)hbuf)[j] = z;
        }
    }
    // Zero the FULL 4096-int flag/ready region.
    if (blockIdx.x < 16) cnt[blockIdx.x * 256 + threadIdx.x] = 0;
}

// ---------------- FUSED kernel: blocks 0..255 = persistent recurrence (the
// proven R1 core, 4 groups x 64 WGs x 256 thr); blocks 256..8447 = x-gates
// GEMM tiles in WINDOW-MAJOR order (all t in [0,128) tiles first, ...).
// The rec waits on per-tile readiness counters rdy[mt] (32 nt-completions
// each) at its 4 window boundaries; the GEMM hides under the latency-bound
// recurrence on the otherwise ~94%-idle machine.
//
// Cross-XCD safety for xg: gemm stores xg with AGENT-scope atomic stores
// (straight to L3 — no dirty-L2 residue), drains vmcnt(0) per thread, joins
// __syncthreads, then one thread bumps rdy[mt] (agent RMW at L3). Consumers
// only touch xg after rdy[mt]==32, so their caches never hold stale copies
// within a dispatch (and dispatch-start invalidates across launches).
// Deadlock-free: rec blocks (256) can never fill the machine; gemm blocks
// depend on nothing.
//
// Rec sync protocol: IDENTICAL to the passing R1 kernel (per-wave flags,
// publish after per-wave vmcnt(0) drain, skew<=1 double-buffered hbuf);
// flags compacted to 4B stride (same mapping, fewer poll lines).
template <typename XGT, typename XG4>
__global__ __launch_bounds__(256, 2) void k_fused(
    const ushort_t* __restrict__ Ab,   // feature bf16 [32768][1024]
    const ushort_t* __restrict__ Bb,   // W_ih' bf16 [4096][1024] (row-permuted)
    const float* __restrict__ bih, const float* __restrict__ bhh,
    const int* __restrict__ slenp,
    XGT* xg, const ushort_t* __restrict__ whhb,
    ushort_t* hbuf, float* __restrict__ out, int* cnt)
{
    extern __shared__ char smem[];     // 32KB dynamic: union of gemm/rec layouts
    int* rdy = cnt + 1024;             // 256 tile counters (ints 1024..1279)

    if (blockIdx.x >= 256) {
        // ================= GEMM tile =================
        int bid2 = blockIdx.x - 256;           // 0..8191
        int w = bid2 >> 11;                    // window 0..3 (t0 = w*128)
        int qq = bid2 & 2047;
        int pp = qq >> 8;                      // 8 sub-panels of (8 b x 32 nt)
        int q2 = qq & 255;
        int bl = (pp << 3) | (q2 & 7);         // batch 0..63
        int nt = q2 >> 3;
        int mt = (bl << 2) | w;                // m-tile id 0..255
        int m0 = mt << 7, n0 = nt << 7;
        int b = bl;
        int t0 = w << 7;
        int sl = slenp[b];
        if (t0 >= sl) {                        // fully masked: publish and leave
            if (threadIdx.x == 0)
                __hip_atomic_fetch_add(&rdy[mt], 1, __ATOMIC_RELAXED, __HIP_MEMORY_SCOPE_AGENT);
            return;
        }

        short8* ldsA8 = (short8*)smem;         // 128 rows x 8 chunks (16KB), swizzled
        short8* ldsB8 = (short8*)(smem + 16384);
        ushort_t* ldsA = (ushort_t*)ldsA8;
        ushort_t* ldsB = (ushort_t*)ldsB8;
        const ushort_t* gA = Ab + (size_t)m0 * 1024;
        const ushort_t* gB = Bb + (size_t)n0 * 1024;

        int tid = threadIdx.x;
        int wave = tid >> 6, lane = tid & 63;
        int wm = (wave >> 1) << 6;
        int wn = (wave & 1) << 6;
        int fl = lane & 15, fq = lane >> 4;

        f32x4 acc[4][4];
#pragma unroll
        for (int i = 0; i < 4; i++)
#pragma unroll
            for (int j = 0; j < 4; j++) { f32x4 z = {0.f, 0.f, 0.f, 0.f}; acc[i][j] = z; }

        int srow_[4], skb_[4];
#pragma unroll
        for (int u = 0; u < 4; u++) {
            int s = u * 256 + tid;
            srow_[u] = s >> 3;
            skb_[u] = (s & 7) ^ (srow_[u] & 7);
        }

        for (int k0 = 0; k0 < 1024; k0 += 64) {
            if (k0) __syncthreads();
#pragma unroll
            for (int u = 0; u < 4; u++) {
                ushort_t* sa = ldsA + (size_t)(u * 256 + wave * 64) * 8;
                ushort_t* sb = ldsB + (size_t)(u * 256 + wave * 64) * 8;
                async_cp16(gA + (size_t)srow_[u] * 1024 + k0 + skb_[u] * 8, sa);
                async_cp16(gB + (size_t)srow_[u] * 1024 + k0 + skb_[u] * 8, sb);
            }
            __syncthreads();
#pragma unroll
            for (int ks = 0; ks < 2; ks++) {
                int kc = ks * 4 + fq;
                short8 af[4], bf[4];
#pragma unroll
                for (int i = 0; i < 4; i++) {
                    int ra = wm + i * 16 + fl;
                    int rb = wn + i * 16 + fl;
                    af[i] = ldsA8[ra * 8 + (kc ^ (ra & 7))];
                    bf[i] = ldsB8[rb * 8 + (kc ^ (rb & 7))];
                }
#pragma unroll
                for (int i = 0; i < 4; i++)
#pragma unroll
                    for (int j = 0; j < 4; j++)
                        acc[i][j] = __builtin_amdgcn_mfma_f32_16x16x32_bf16(af[i], bf[j], acc[i][j], 0, 0, 0);
            }
        }
        // epilogue: agent-scope stores (straight to L3)
#pragma unroll
        for (int j = 0; j < 4; j++) {
            int rp = n0 + wn + j * 16 + fl;
            int bi = ((rp & 3) << 10) | (rp >> 2);
            float bv = bih[bi] + bhh[bi];
#pragma unroll
            for (int i = 0; i < 4; i++) {
#pragma unroll
                for (int r = 0; r < 4; r++) {
                    int m = wm + i * 16 + fq * 4 + r;
                    int t = t0 + m;
                    if (t < sl)
                        xg_astore(&xg[((size_t)t * 64 + b) * 4096 + rp], acc[i][j][r] + bv);
                }
            }
        }
        asm volatile("s_waitcnt vmcnt(0)" ::: "memory");   // own stores in L3
        __syncthreads();                                   // all threads drained
        if (threadIdx.x == 0)
            __hip_atomic_fetch_add(&rdy[mt], 1, __ATOMIC_RELAXED, __HIP_MEMORY_SCOPE_AGENT);
        return;
    }

    // ================= RECURRENCE (proven R1 core) =================
    const XG4* xg4 = (const XG4*)xg;
    const int tid = threadIdx.x;
    const int ks = tid >> 6, lane = tid & 63;      // wave = K-quarter
    const int wg = blockIdx.x;
    const int mb = wg >> 6;            // 0..3 batch block
    const int mem = wg & 63;           // member within group
    const int j0 = mem << 4;           // 16 j per WG
    const int nn = lane & 15, q = lane >> 4;

    // B-fragments: 4 gates x 16 j rows at K-quarter ks, resident in VGPRs
    short8 wfrag[4][8];
    {
        const short8* w8 = (const short8*)whhb;
#pragma unroll
        for (int g = 0; g < 4; g++) {
            const short8* wp = w8 + (size_t)(g * NHH + j0 + nn) * 128 + ks * 32;
#pragma unroll
            for (int u = 0; u < 8; u++) wfrag[g][u] = wp[u * 4 + q];
        }
    }
    const int eb = tid >> 4, ej = tid & 15;
    const int b_g = (mb << 4) + eb;    // epilogue thread's (batch, j)
    const int j_g = j0 + ej;
    const int slen = slenp[b_g];
    const int blk_len = slenp[mb << 4]; // seq_len sorted desc -> block max
    const int ab = (mb << 4) + nn;     // A-frag batch row for this lane

    // compact flags (4B stride): group region = 256 ints at cnt + mb*256.
    // flag (mem, wave w) at mem*4 + w; consumer wave ks lane l polls
    // member ks*16 + (l>>2), wave l&3 — same covering map as R1.
    int* flags = cnt + mb * 256;
    int* myflag = flags + mem * 4 + ks;
    const int* fp = flags + (ks * 16 + (lane >> 2)) * 4 + (lane & 3);

    // xg window wait: window w2 ready when rdy[b*4 + w2] == 32 for all 16
    // batches of this group (lane&15 covers them; lanes 16+ duplicate).
    const int ridx = ((mb << 4) + (lane & 15)) << 2;
    auto waitwin = [&](int w2) {
        int guard = 0;
        while (true) {
            int f = __hip_atomic_load(&rdy[ridx + w2], __ATOMIC_RELAXED, __HIP_MEMORY_SCOPE_AGENT);
            if (__ballot(f >= 32) == ~0ull) break;
            if (++guard > (1 << 20)) break;   // bounded: bug -> visible fail
            __builtin_amdgcn_s_sleep(8);
        }
        asm volatile("" ::: "memory");
    };

    // ks-reduction buffer: [g][j 16][ks 4][b 16], j-stride 84, ks-stride 20
    float* red = (float*)smem;   // 21504 B

    float c_st = 0.f, h_st = 0.f, hv_prev = 0.f;
    waitwin(0);
    float4v xv = { 0.f, 0.f, 0.f, 0.f };
    if (0 < slen) xv = xg_load4(&xg4[(size_t)b_g * 1024 + j_g]);   // xg(0)

#pragma unroll 1
    for (int t = 0; t < blk_len; ++t) {
        // deferred out store for t-1 (off critical path)
        if (t > 0) out[((size_t)b_g * NT + (t - 1)) * 1024 + j_g] = hv_prev;
        // window gate, then prefetch xg(t+1): in flight across the whole step
        if (t + 1 < blk_len && ((t + 1) & 127) == 0) waitwin((t + 1) >> 7);
        float4v nxv = { 0.f, 0.f, 0.f, 0.f };
        if (t + 1 < slen) nxv = xg_load4(&xg4[((size_t)(t + 1) * 64 + b_g) * 1024 + j_g]);

        if (t > 0) {
            // one-hop wait: this wave's 64 producer wave-flags must reach t
            int guard = 0;
            while (true) {
                int f = __hip_atomic_load(fp, __ATOMIC_RELAXED, __HIP_MEMORY_SCOPE_AGENT);
                if (__ballot(f >= t) == ~0ull) break;
                if (++guard > (1 << 20)) break;
            }
            asm volatile("" ::: "memory");   // keep h loads below the poll
        }

        const ull_t* hb8 = (const ull_t*)(hbuf + (size_t)(t & 1) * 65536);
        // A: 8 x 16B agent loads (disjoint K-quarter per wave)
        ull_t raw[16];
#pragma unroll
        for (int u = 0; u < 8; u++) {
            size_t ch = ((size_t)((ks * 32 + u * 4 + q) * 64 + ab)) * 2;
            raw[2 * u]     = __hip_atomic_load(&hb8[ch],     __ATOMIC_RELAXED, __HIP_MEMORY_SCOPE_AGENT);
            raw[2 * u + 1] = __hip_atomic_load(&hb8[ch + 1], __ATOMIC_RELAXED, __HIP_MEMORY_SCOPE_AGENT);
        }
        f32x4 acc[4];
#pragma unroll
        for (int g = 0; g < 4; g++) { f32x4 z = {0.f, 0.f, 0.f, 0.f}; acc[g] = z; }
#pragma unroll
        for (int u = 0; u < 8; u++) {
            ull2 p; p[0] = raw[2 * u]; p[1] = raw[2 * u + 1];
            short8 af = __builtin_bit_cast(short8, p);
#pragma unroll
            for (int g = 0; g < 4; g++)
                acc[g] = __builtin_amdgcn_mfma_f32_16x16x32_bf16(af, wfrag[g][u], acc[g], 0, 0, 0);
        }
        __syncthreads();   // red consumed last step
#pragma unroll
        for (int g = 0; g < 4; g++)
            *(f32x4*)&red[g * 1344 + nn * 84 + ks * 20 + q * 4] = acc[g];
        __syncthreads();   // red ready (anchor of the skew<=1 proof)

        float hv = 0.f;
        if (t < slen) {
            float s[4];
#pragma unroll
            for (int g = 0; g < 4; g++) {
                const float* rp = &red[g * 1344 + ej * 84 + eb];
                s[g] = (rp[0] + rp[20]) + (rp[40] + rp[60]);
            }
            float ip = s[0] + xv[0];
            float fpv = s[1] + xv[1];
            float gp = s[2] + xv[2];
            float op = s[3] + xv[3];
            float i_s = fsigmoid(ip), f_s = fsigmoid(fpv);
            float g_t = ftanh(gp), o_s = fsigmoid(op);
            float cn = __builtin_fmaf(f_s, c_st, i_s * g_t);
            c_st = cn;
            h_st = o_s * ftanh(cn);
            hv = h_st;
        }
        hv_prev = hv;
        // h store: agent-scope fine-grained (visible at L3 once vmcnt drains)
        __hip_atomic_store(&hbuf[(size_t)((t + 1) & 1) * 65536 +
                                 (size_t)((j_g >> 3) * 64 + b_g) * 8 + (j_g & 7)],
                           f2bf(h_st), __ATOMIC_RELAXED, __HIP_MEMORY_SCOPE_AGENT);
        // drain own vmem (h store must be at L3 before flag), then publish
        asm volatile("s_waitcnt vmcnt(0)" ::: "memory");
        if (lane == 0)
            __hip_atomic_store(myflag, t + 1, __ATOMIC_RELAXED, __HIP_MEMORY_SCOPE_AGENT);
        xv = nxv;
    }
    // tail: last h output + zero padding past blk_len
    out[((size_t)b_g * NT + (blk_len - 1)) * 1024 + j_g] = hv_prev;
    for (int t = blk_len; t < NT; ++t)
        out[((size_t)b_g * NT + t) * 1024 + j_g] = 0.f;
}

extern "C" void kernel_launch(void* const* d_in, const int* in_sizes, int n_in,
                              void* d_out, int out_size, void* d_ws, size_t ws_size,
                              hipStream_t stream)
{
    const float* feat = (const float*)d_in[0];
    const float* wih  = (const float*)d_in[1];
    const float* whh  = (const float*)d_in[2];
    const float* bih  = (const float*)d_in[3];
    const float* bhh  = (const float*)d_in[4];
    const int*   sl   = (const int*)d_in[5];
    float* out = (float*)d_out;
    char* ws = (char*)d_ws;

    size_t off = 0;
    auto take = [&](size_t bytes) -> size_t {
        size_t o = off; off += (bytes + 255) & ~(size_t)255; return o;
    };
    // FOOTPRINT FROZEN to the proven R1 layout (fp32-xg branch must not flip).
    size_t o_featb = take((size_t)NB * NT * ND * 2);  // 64 MiB
    size_t o_wihb  = take((size_t)NG * ND * 2);       // 8 MiB
    size_t o_whhb  = take((size_t)NG * ND * 2);       // 8 MiB
    size_t o_hbuf  = take((size_t)2 * 65536 * 2);     // 256 KiB (2 bf16 h buffers)
    size_t o_cnt   = take(16384);                     // flags(1KB)+rdy(1KB)+spare
    size_t o_xg    = off;

    ushort_t* featb = (ushort_t*)(ws + o_featb);
    ushort_t* wihb  = (ushort_t*)(ws + o_wihb);
    ushort_t* whhb  = (ushort_t*)(ws + o_whhb);
    ushort_t* hbuf  = (ushort_t*)(ws + o_hbuf);
    int* cnt        = (int*)(ws + o_cnt);

    k_prep<<<2048, 256, 0, stream>>>(feat, wih, whh, featb, wihb, whhb, hbuf, cnt);

    size_t xg_elems = (size_t)NT * NB * NG;
    bool f32xg = (o_xg + xg_elems * 4) <= ws_size;    // prefer fp32 xg for accuracy
    if (f32xg) {
        float* xg = (float*)(ws + o_xg);
        k_fused<float, float4v><<<8448, 256, 32768, stream>>>(
            featb, wihb, bih, bhh, sl, xg, whhb, hbuf, out, cnt);
    } else {
        ushort_t* xg = (ushort_t*)(ws + o_xg);
        k_fused<ushort_t, ushort4v><<<8448, 256, 32768, stream>>>(
            featb, wihb, bih, bhh, sl, xg, whhb, hbuf, out, cnt);
    }
}

// Round 6
// 2409.233 us; speedup vs baseline: 1.2051x; 1.1073x over previous
//
#include <hip/hip_runtime.h>
#include <stdint.h>

typedef unsigned short ushort_t;
typedef unsigned long long ull_t;
typedef __attribute__((ext_vector_type(8))) short short8;      // 8 bf16 (4 VGPRs)
typedef __attribute__((ext_vector_type(2))) unsigned long long ull2;
typedef __attribute__((ext_vector_type(4))) float f32x4;       // MFMA 16x16 acc
typedef __attribute__((ext_vector_type(4))) float float4v;
typedef __attribute__((ext_vector_type(4))) unsigned short ushort4v;
typedef __attribute__((ext_vector_type(4))) unsigned int uint4v;

#define NB 64
#define NT 512
#define ND 1024
#define NHH 1024
#define NG 4096

__device__ __forceinline__ ushort_t f2bf(float x) {
    uint32_t u = __builtin_bit_cast(uint32_t, x);
    u += 0x7fffu + ((u >> 16) & 1u);   // RTNE
    return (ushort_t)(u >> 16);
}
__device__ __forceinline__ float bf2f(ushort_t b) {
    uint32_t u = ((uint32_t)b) << 16;
    return __builtin_bit_cast(float, u);
}
__device__ __forceinline__ float fsigmoid(float x) { return 1.f / (1.f + __expf(-x)); }
__device__ __forceinline__ float ftanh(float x) {
    float ax = __builtin_fabsf(x);
    float e = __expf(-2.f * ax);
    float r = (1.f - e) / (1.f + e);
    return x < 0.f ? -r : r;
}
__device__ __forceinline__ void xg_store(float* p, float v) { *p = v; }
__device__ __forceinline__ void xg_store(ushort_t* p, float v) { *p = f2bf(v); }
__device__ __forceinline__ float4v xg_load4(const float4v* p) { return *p; }
__device__ __forceinline__ float4v xg_load4(const ushort4v* p) {
    ushort4v u = *p;
    float4v r = { bf2f(u[0]), bf2f(u[1]), bf2f(u[2]), bf2f(u[3]) };
    return r;
}
// async global->LDS 16B copy: LDS dest is wave-uniform base + lane*16
__device__ __forceinline__ void async_cp16(const ushort_t* g, ushort_t* s) {
    __builtin_amdgcn_global_load_lds(
        (const __attribute__((address_space(1))) uint32_t*)g,
        (__attribute__((address_space(3))) uint32_t*)s, 16, 0, 0);
}

// ---------------- prep: fp32->bf16 conversions (W_ih row-PERMUTED), h buffers:
// parity 0 = zeros (valid h(0), tagbit 0); parity 1 = 0x0001 pattern (bit0=1,
// MISmatches tagbit(1)=0 so step-1 consumers spin until real h(1) arrives).
__global__ __launch_bounds__(256) void k_prep(
    const float* __restrict__ feat, const float* __restrict__ wih,
    const float* __restrict__ whh,
    ushort_t* __restrict__ featb, ushort_t* __restrict__ wihb,
    ushort_t* __restrict__ whhb, ushort_t* __restrict__ hbuf,
    int* __restrict__ cnt)
{
    const size_t NF = (size_t)NB * NT * ND / 4;   // 8388608 float4 chunks
    const size_t NW = (size_t)NG * ND / 4;        // 1048576
    const size_t NHB = (size_t)2 * 65536 * 2 / 16; // 16384 16B chunks
    size_t total = NF + 2 * NW + NHB;
    size_t stride = (size_t)gridDim.x * blockDim.x;
    for (size_t i = (size_t)blockIdx.x * blockDim.x + threadIdx.x; i < total; i += stride) {
        if (i < NF) {
            float4v v = ((const float4v*)feat)[i];
            ushort4v o = { f2bf(v[0]), f2bf(v[1]), f2bf(v[2]), f2bf(v[3]) };
            ((ushort4v*)featb)[i] = o;
        } else if (i < NF + NW) {
            size_t j = i - NF;                      // chunk over [4096 rows][256 f4]
            size_t row = j >> 8, kc = j & 255;
            size_t rowp = ((row & 1023) << 2) | (row >> 10);   // j*4 + gate
            float4v v = ((const float4v*)wih)[j];
            ushort4v o = { f2bf(v[0]), f2bf(v[1]), f2bf(v[2]), f2bf(v[3]) };
            ((ushort4v*)wihb)[rowp * 256 + kc] = o;
        } else if (i < NF + 2 * NW) {
            size_t j = i - NF - NW;
            float4v v = ((const float4v*)whh)[j];
            ushort4v o = { f2bf(v[0]), f2bf(v[1]), f2bf(v[2]), f2bf(v[3]) };
            ((ushort4v*)whhb)[j] = o;
        } else {
            size_t j = i - NF - 2 * NW;             // 16B chunk of hbuf
            uint32_t fill = (j < 8192) ? 0u : 0x00010001u;  // parity1: tag bit set
            uint4v z = { fill, fill, fill, fill };
            ((uint4v*)hbuf)[j] = z;
        }
    }
    // Zero the flag region (unused this round; footprint frozen).
    if (blockIdx.x < 16) cnt[blockIdx.x * 256 + threadIdx.x] = 0;
}

// ---------------- x_gates GEMM: IDENTICAL to the proven R1 version.
template <typename XGT>
__global__ __launch_bounds__(256) void k_gemm(
    const ushort_t* __restrict__ Ab,   // feature bf16 [32768][1024]
    const ushort_t* __restrict__ Bb,   // W_ih' bf16 [4096][1024] (row-permuted)
    const float* __restrict__ bih, const float* __restrict__ bhh,
    const int* __restrict__ slenp, XGT* __restrict__ xg)
{
    int bid = blockIdx.x;                  // 8192 tiles
    int panel = bid >> 8;                  // 32 panels of (8 mt x 32 nt) for L2 reuse
    int qq = bid & 255;
    int mt = (panel << 3) | (qq & 7);
    int nt = qq >> 3;
    int m0 = mt << 7, n0 = nt << 7;
    int b = m0 >> 9;                       // 128-row tile lies within one batch
    int t0 = m0 & 511;
    int sl = slenp[b];
    if (t0 >= sl) return;                  // whole tile masked: xg never read there

    __shared__ short8 ldsA8[1024];         // 128 rows x 8 chunks (16 KB), swizzled
    __shared__ short8 ldsB8[1024];
    ushort_t* ldsA = (ushort_t*)ldsA8;
    ushort_t* ldsB = (ushort_t*)ldsB8;
    const ushort_t* gA = Ab + (size_t)m0 * 1024;
    const ushort_t* gB = Bb + (size_t)n0 * 1024;

    int tid = threadIdx.x;
    int wave = tid >> 6, lane = tid & 63;
    int wm = (wave >> 1) << 6;
    int wn = (wave & 1) << 6;
    int fl = lane & 15, fq = lane >> 4;

    f32x4 acc[4][4];
#pragma unroll
    for (int i = 0; i < 4; i++)
#pragma unroll
        for (int j = 0; j < 4; j++) { f32x4 z = {0.f, 0.f, 0.f, 0.f}; acc[i][j] = z; }

    // per-thread staging coords: slot s = u*256 + tid; row = s>>3, kb = (s&7)^(row&7)
    int srow_[4], skb_[4];
#pragma unroll
    for (int u = 0; u < 4; u++) {
        int s = u * 256 + tid;
        srow_[u] = s >> 3;
        skb_[u] = (s & 7) ^ (srow_[u] & 7);
    }

    for (int k0 = 0; k0 < 1024; k0 += 64) {
        if (k0) __syncthreads();           // protect LDS from previous iter's reads
#pragma unroll
        for (int u = 0; u < 4; u++) {
            ushort_t* sa = ldsA + (size_t)(u * 256 + wave * 64) * 8;
            ushort_t* sb = ldsB + (size_t)(u * 256 + wave * 64) * 8;
            async_cp16(gA + (size_t)srow_[u] * 1024 + k0 + skb_[u] * 8, sa);
            async_cp16(gB + (size_t)srow_[u] * 1024 + k0 + skb_[u] * 8, sb);
        }
        __syncthreads();                   // drains vmcnt: LDS tiles ready
#pragma unroll
        for (int ks = 0; ks < 2; ks++) {
            int kc = ks * 4 + fq;          // 16B chunk within BK=64
            short8 af[4], bf[4];
#pragma unroll
            for (int i = 0; i < 4; i++) {
                int ra = wm + i * 16 + fl;
                int rb = wn + i * 16 + fl;
                af[i] = ldsA8[ra * 8 + (kc ^ (ra & 7))];
                bf[i] = ldsB8[rb * 8 + (kc ^ (rb & 7))];
            }
#pragma unroll
            for (int i = 0; i < 4; i++)
#pragma unroll
                for (int j = 0; j < 4; j++)
                    acc[i][j] = __builtin_amdgcn_mfma_f32_16x16x32_bf16(af[i], bf[j], acc[i][j], 0, 0, 0);
        }
    }
    // epilogue: C layout col=lane&15, row=quad*4+reg. Columns are permuted rows rp.
#pragma unroll
    for (int j = 0; j < 4; j++) {
        int rp = n0 + wn + j * 16 + fl;              // permuted row index
        int bi = ((rp & 3) << 10) | (rp >> 2);       // gate*1024 + j
        float bv = bih[bi] + bhh[bi];
#pragma unroll
        for (int i = 0; i < 4; i++) {
#pragma unroll
            for (int r = 0; r < 4; r++) {
                int m = wm + i * 16 + fq * 4 + r;
                int t = t0 + m;
                if (t < sl)
                    xg_store(&xg[((size_t)t * 64 + b) * 4096 + rp], acc[i][j][r] + bv);
            }
        }
    }
}

// ---------------- persistent recurrence: TAGGED-H (flag-free), R1 structure.
// 256 WGs x 256 thr, group mb = wg>>6 owns 16 batches, member mem = wg&63 owns
// 16 j. Wave ks = K-quarter. IDENTICAL compute core to the passing R1 kernel.
//
// Sync: h stored as bf16 with BIT 0 STOLEN as a validity tag:
//   stored = (bf16(h) & ~1) | tagbit,  tagbit(t) = (t>>1)&1
// Producer publishes with ONE plain agent-scope 2B store — no vmcnt drain, no
// flag. Consumer spin-loads its 16 data ulls and checks the 4 embedded tag
// bits per load: detect and data arrive in the SAME L3 round trip. Per-ull
// pending mask avoids re-loading validated words; s_sleep(1) on failed rounds
// bounds poll traffic.
// Skew<=1 proof (unchanged shape): my h(t+1) store follows bar F(t), which
// joins threads whose spins validated EVERY word of h(t); each h(t) word was
// stored by its producer AFTER that producer's bar F(t-1), i.e. after its WG
// consumed all h(t-1) loads -> overwriting parity (t+1)&1 == (t-1)&1 is safe.
// 1-bit tag suffices: a slot holds either h(t) (tag match) or h(t-2) (tag
// mismatch); deeper staleness is excluded by skew<=1. Parity-1 init has bit0=1
// so the zero-init can't masquerade as h(1) (tagbit(1)=0).
template <typename XG4>
__global__ __launch_bounds__(256, 1) void k_rec(
    const ushort_t* __restrict__ whhb, const XG4* __restrict__ xg4,
    const int* __restrict__ slenp, ushort_t* __restrict__ hbuf,
    float* __restrict__ out, int* __restrict__ cnt)
{
    (void)cnt;   // flags retired; region kept for frozen footprint
    const int tid = threadIdx.x;
    const int ks = tid >> 6, lane = tid & 63;      // wave = K-quarter
    const int wg = blockIdx.x;
    const int mb = wg >> 6;            // 0..3 batch block
    const int mem = wg & 63;           // member within group
    const int j0 = mem << 4;           // 16 j per WG
    const int nn = lane & 15, q = lane >> 4;

    // B-fragments: 4 gates x 16 j rows at K-quarter ks, resident in VGPRs
    short8 wfrag[4][8];
    {
        const short8* w8 = (const short8*)whhb;
#pragma unroll
        for (int g = 0; g < 4; g++) {
            const short8* wp = w8 + (size_t)(g * NHH + j0 + nn) * 128 + ks * 32;
#pragma unroll
            for (int u = 0; u < 8; u++) wfrag[g][u] = wp[u * 4 + q];
        }
    }
    const int eb = tid >> 4, ej = tid & 15;
    const int b_g = (mb << 4) + eb;    // epilogue thread's (batch, j)
    const int j_g = j0 + ej;
    const int slen = slenp[b_g];
    const int blk_len = slenp[mb << 4]; // seq_len sorted desc -> block max
    const int ab = (mb << 4) + nn;     // A-frag batch row for this lane

    // ks-reduction buffer: [g][j 16][ks 4][b 16], j-stride 84 floats, ks-stride 20
    __shared__ float red[4 * 16 * 84];   // 21504 B

    const ull_t TMASK = 0x0001000100010001ull;

    float c_st = 0.f, h_st = 0.f, hv_prev = 0.f;
    float4v xv = { 0.f, 0.f, 0.f, 0.f };
    if (0 < slen) xv = xg_load4(&xg4[(size_t)b_g * 1024 + j_g]);   // xg(0)

#pragma unroll 1
    for (int t = 0; t < blk_len; ++t) {
        // deferred out store for t-1 (off critical path)
        if (t > 0) out[((size_t)b_g * NT + (t - 1)) * 1024 + j_g] = hv_prev;
        // prefetch xg(t+1): in flight across the whole step
        float4v nxv = { 0.f, 0.f, 0.f, 0.f };
        if (t + 1 < slen) nxv = xg_load4(&xg4[((size_t)(t + 1) * 64 + b_g) * 1024 + j_g]);

        // spin: load+validate h(t) — detect and data in one L3 round trip.
        const ull_t* hb8 = (const ull_t*)(hbuf + (size_t)(t & 1) * 65536);
        const ull_t texp = ((t >> 1) & 1) ? TMASK : 0ull;
        ull_t raw[16];
        uint32_t pend;
        {
            // round 0: unconditional load of all 16 (assigns every raw[])
            pend = 0xffffu;
#pragma unroll
            for (int u = 0; u < 8; u++) {
                size_t ch = ((size_t)((ks * 32 + u * 4 + q) * 64 + ab)) * 2;
                ull_t x0 = __hip_atomic_load(&hb8[ch],     __ATOMIC_RELAXED, __HIP_MEMORY_SCOPE_AGENT);
                ull_t x1 = __hip_atomic_load(&hb8[ch + 1], __ATOMIC_RELAXED, __HIP_MEMORY_SCOPE_AGENT);
                raw[2 * u] = x0; raw[2 * u + 1] = x1;
                if ((x0 & TMASK) == texp) pend &= ~(1u << (2 * u));
                if ((x1 & TMASK) == texp) pend &= ~(1u << (2 * u + 1));
            }
        }
        int guard = 0;
        while (pend) {
            __builtin_amdgcn_s_sleep(1);
#pragma unroll
            for (int u = 0; u < 8; u++) {
                size_t ch = ((size_t)((ks * 32 + u * 4 + q) * 64 + ab)) * 2;
                if (pend & (1u << (2 * u))) {
                    ull_t x = __hip_atomic_load(&hb8[ch], __ATOMIC_RELAXED, __HIP_MEMORY_SCOPE_AGENT);
                    if ((x & TMASK) == texp) { raw[2 * u] = x; pend &= ~(1u << (2 * u)); }
                }
                if (pend & (1u << (2 * u + 1))) {
                    ull_t x = __hip_atomic_load(&hb8[ch + 1], __ATOMIC_RELAXED, __HIP_MEMORY_SCOPE_AGENT);
                    if ((x & TMASK) == texp) { raw[2 * u + 1] = x; pend &= ~(1u << (2 * u + 1)); }
                }
            }
            if (++guard > (1 << 20)) break;   // bounded: bug -> visible fail
        }

        f32x4 acc[4];
#pragma unroll
        for (int g = 0; g < 4; g++) { f32x4 z = {0.f, 0.f, 0.f, 0.f}; acc[g] = z; }
#pragma unroll
        for (int u = 0; u < 8; u++) {
            ull2 p; p[0] = raw[2 * u]; p[1] = raw[2 * u + 1];
            short8 af = __builtin_bit_cast(short8, p);
#pragma unroll
            for (int g = 0; g < 4; g++)
                acc[g] = __builtin_amdgcn_mfma_f32_16x16x32_bf16(af, wfrag[g][u], acc[g], 0, 0, 0);
        }
        __syncthreads();   // red consumed last step
#pragma unroll
        for (int g = 0; g < 4; g++)
            *(f32x4*)&red[g * 1344 + nn * 84 + ks * 20 + q * 4] = acc[g];
        __syncthreads();   // bar F: red ready (anchor of the skew<=1 proof)

        float hv = 0.f;
        if (t < slen) {
            float s[4];
#pragma unroll
            for (int g = 0; g < 4; g++) {
                const float* rp = &red[g * 1344 + ej * 84 + eb];
                s[g] = (rp[0] + rp[20]) + (rp[40] + rp[60]);
            }
            float ip = s[0] + xv[0];
            float fp = s[1] + xv[1];
            float gp = s[2] + xv[2];
            float op = s[3] + xv[3];
            float i_s = fsigmoid(ip), f_s = fsigmoid(fp);
            float g_t = ftanh(gp), o_s = fsigmoid(op);
            float cn = __builtin_fmaf(f_s, c_st, i_s * g_t);
            c_st = cn;
            h_st = o_s * ftanh(cn);
            hv = h_st;
        }
        hv_prev = hv;
        // tagged h(t+1) publish: ONE 2B agent store; no drain, no flag.
        ushort_t hw = (ushort_t)((f2bf(h_st) & 0xFFFEu) | (uint32_t)(((t + 1) >> 1) & 1));
        __hip_atomic_store(&hbuf[(size_t)((t + 1) & 1) * 65536 +
                                 (size_t)((j_g >> 3) * 64 + b_g) * 8 + (j_g & 7)],
                           hw, __ATOMIC_RELAXED, __HIP_MEMORY_SCOPE_AGENT);
        xv = nxv;
    }
    // tail: last h output + zero padding past blk_len
    out[((size_t)b_g * NT + (blk_len - 1)) * 1024 + j_g] = hv_prev;
    for (int t = blk_len; t < NT; ++t)
        out[((size_t)b_g * NT + t) * 1024 + j_g] = 0.f;
}

extern "C" void kernel_launch(void* const* d_in, const int* in_sizes, int n_in,
                              void* d_out, int out_size, void* d_ws, size_t ws_size,
                              hipStream_t stream)
{
    const float* feat = (const float*)d_in[0];
    const float* wih  = (const float*)d_in[1];
    const float* whh  = (const float*)d_in[2];
    const float* bih  = (const float*)d_in[3];
    const float* bhh  = (const float*)d_in[4];
    const int*   sl   = (const int*)d_in[5];
    float* out = (float*)d_out;
    char* ws = (char*)d_ws;

    size_t off = 0;
    auto take = [&](size_t bytes) -> size_t {
        size_t o = off; off += (bytes + 255) & ~(size_t)255; return o;
    };
    // FOOTPRINT FROZEN to the proven R1 layout (fp32-xg branch must not flip).
    size_t o_featb = take((size_t)NB * NT * ND * 2);  // 64 MiB
    size_t o_wihb  = take((size_t)NG * ND * 2);       // 8 MiB
    size_t o_whhb  = take((size_t)NG * ND * 2);       // 8 MiB
    size_t o_hbuf  = take((size_t)2 * 65536 * 2);     // 256 KiB (2 bf16 h buffers)
    size_t o_cnt   = take(16384);                     // retired flag region (frozen)
    size_t o_xg    = off;

    ushort_t* featb = (ushort_t*)(ws + o_featb);
    ushort_t* wihb  = (ushort_t*)(ws + o_wihb);
    ushort_t* whhb  = (ushort_t*)(ws + o_whhb);
    ushort_t* hbuf  = (ushort_t*)(ws + o_hbuf);
    int* cnt        = (int*)(ws + o_cnt);

    k_prep<<<2048, 256, 0, stream>>>(feat, wih, whh, featb, wihb, whhb, hbuf, cnt);

    size_t xg_elems = (size_t)NT * NB * NG;
    bool f32xg = (o_xg + xg_elems * 4) <= ws_size;    // prefer fp32 xg for accuracy
    if (f32xg) {
        float* xg = (float*)(ws + o_xg);
        k_gemm<float><<<8192, 256, 0, stream>>>(featb, wihb, bih, bhh, sl, xg);
        k_rec<float4v><<<256, 256, 0, stream>>>(whhb, (const float4v*)xg, sl, hbuf, out, cnt);
    } else {
        ushort_t* xg = (ushort_t*)(ws + o_xg);
        k_gemm<ushort_t><<<8192, 256, 0, stream>>>(featb, wihb, bih, bhh, sl, xg);
        k_rec<ushort4v><<<256, 256, 0, stream>>>(whhb, (const ushort4v*)xg, sl, hbuf, out, cnt);
    }
}